// Round 20
// baseline (180.844 us; speedup 1.0000x reference)
//
#include <hip/hip_runtime.h>

#define HIDDEN 768
#define NHEAD 12
#define HDIM 64
#define SEQ 512
#define BATCH 32
#define MTOT (BATCH*SEQ)   // 16384

typedef __attribute__((ext_vector_type(8))) short short8;
typedef __attribute__((ext_vector_type(4))) float f32x4;
typedef __attribute__((ext_vector_type(4))) unsigned short us4;

#define LOG2E 1.44269504088896340736f

__device__ __forceinline__ unsigned short f2bf(float f){
  unsigned u = __builtin_bit_cast(unsigned, f);
  u += 0x7fff + ((u >> 16) & 1);   // RNE
  return (unsigned short)(u >> 16);
}

__device__ __forceinline__ float bf2f(unsigned short s){
  unsigned u = ((unsigned)s) << 16;
  return __builtin_bit_cast(float, u);
}

// bare v_exp_f32 (2^x); s_nop covers the TRANS->consumer wait-state hazard
__device__ __forceinline__ float fexp2(float x){
  float r;
  asm("v_exp_f32 %0, %1\n\ts_nop 0" : "=v"(r) : "v"(x));
  return r;
}

__device__ __forceinline__ void gload16(unsigned short* lds, const unsigned short* g){
  __builtin_amdgcn_global_load_lds(
      (const __attribute__((address_space(1))) void*)g,
      (__attribute__((address_space(3))) void*)lds, 16, 0, 0);
}

// ---------------- fp32 -> bf16 conversion: x + 4 weights in ONE launch ----------------
#define XF4   (MTOT*HIDDEN/4)
#define WF4   (HIDDEN*HIDDEN/4)
__global__ __launch_bounds__(256) void cvt_all(
    const float* __restrict__ x,
    const float* __restrict__ w0, const float* __restrict__ w1,
    const float* __restrict__ w2, const float* __restrict__ w3,
    unsigned short* __restrict__ xo,
    unsigned short* __restrict__ o0, unsigned short* __restrict__ o1,
    unsigned short* __restrict__ o2, unsigned short* __restrict__ o3){
  int idx = blockIdx.x * blockDim.x + threadIdx.x;
  const float* in;
  unsigned short* out;
  int off;
  if (idx < XF4) { in = x; out = xo; off = idx; }
  else {
    int widx = idx - XF4;
    int which = widx / WF4;
    off = widx - which * WF4;
    in  = (which==0)?w0:((which==1)?w1:((which==2)?w2:w3));
    out = (which==0)?o0:((which==1)?o1:((which==2)?o2:o3));
  }
  float4 v = ((const float4*)in)[off];
  ushort4 o;
  o.x = f2bf(v.x); o.y = f2bf(v.y); o.z = f2bf(v.z); o.w = f2bf(v.w);
  ((ushort4*)out)[off] = o;
}

// ====== 256x192 GEMM, BK=64, 4m x 2n waves, counted-lgkm sub-phase body ======
// Shared compute body (reads+MFMA for one K-tile) used by both variants.
#define TILE_BODY(bA, bB) \
  { \
    short8 af0[4], bf0[6], af1[4], bf1[6]; \
    _Pragma("unroll") \
    for (int i = 0; i < 4; i++) af0[i] = *(const short8*)&(bA)[aoff[i]]; \
    _Pragma("unroll") \
    for (int i = 0; i < 6; i++) bf0[i] = *(const short8*)&(bB)[boff[i]]; \
    __builtin_amdgcn_sched_barrier(0); \
    _Pragma("unroll") \
    for (int i = 0; i < 4; i++) af1[i] = *(const short8*)&(bA)[aoff[i] ^ 32]; \
    _Pragma("unroll") \
    for (int i = 0; i < 6; i++) bf1[i] = *(const short8*)&(bB)[boff[i] ^ 32]; \
    asm volatile("s_waitcnt lgkmcnt(10)" ::: "memory"); \
    __builtin_amdgcn_sched_barrier(0); \
    __builtin_amdgcn_s_setprio(1); \
    _Pragma("unroll") \
    for (int mi2 = 0; mi2 < 4; mi2++) \
      _Pragma("unroll") \
      for (int ni = 0; ni < 6; ni++) \
        acc[mi2][ni] = __builtin_amdgcn_mfma_f32_16x16x32_bf16(af0[mi2], bf0[ni], acc[mi2][ni], 0, 0, 0); \
    __builtin_amdgcn_s_setprio(0); \
    asm volatile("s_waitcnt lgkmcnt(0)" ::: "memory"); \
    __builtin_amdgcn_sched_barrier(0); \
    __builtin_amdgcn_s_setprio(1); \
    _Pragma("unroll") \
    for (int mi2 = 0; mi2 < 4; mi2++) \
      _Pragma("unroll") \
      for (int ni = 0; ni < 6; ni++) \
        acc[mi2][ni] = __builtin_amdgcn_mfma_f32_16x16x32_bf16(af1[mi2], bf1[ni], acc[mi2][ni], 0, 0, 0); \
    __builtin_amdgcn_s_setprio(0); \
  }

// ---- single-buffered variant (56KB LDS -> 2 blocks/CU; drain covered by partner block)
#define SB_STAGE(kt_) do { \
    const int kc_ = (kt_)*64; \
    gload16(&sA1[(size_t)(tid)*8],      gA + kc_); \
    gload16(&sA1[(size_t)(512+tid)*8],  gA + (size_t)64*HIDDEN + kc_); \
    gload16(&sA1[(size_t)(1024+tid)*8], gA + (size_t)128*HIDDEN + kc_); \
    gload16(&sA1[(size_t)(1536+tid)*8], gA + (size_t)192*HIDDEN + kc_); \
    gload16(&sB1[(size_t)(tid)*8],      gB + kc_); \
    gload16(&sB1[(size_t)(512+tid)*8],  gB + (size_t)64*HIDDEN + kc_); \
    gload16(&sB1[(size_t)(1024+tid)*8], gB + (size_t)128*HIDDEN + kc_); \
  } while(0)

#define GEMM_MAIN_SB() \
  SB_STAGE(0); \
  for (int kt = 0; kt < 12; ++kt) { \
    __syncthreads();   /* stage(kt) landed: compiler drains vmcnt before barrier */ \
    TILE_BODY(sA1, sB1); \
    if (kt < 11) { \
      __syncthreads(); /* all reads of this tile consumed before overwrite */ \
      SB_STAGE(kt+1); \
    } \
  }

// ---- double-buffered variant (112KB LDS; for proj's 256-block 1/CU grid)
#define STAGE_A(buf, kt_) do { \
    const int kc_ = (kt_)*64; \
    gload16(&sA[buf][(size_t)(tid)*8],      gA + kc_); \
    gload16(&sA[buf][(size_t)(512+tid)*8],  gA + (size_t)64*HIDDEN + kc_); \
    gload16(&sA[buf][(size_t)(1024+tid)*8], gA + (size_t)128*HIDDEN + kc_); \
    gload16(&sA[buf][(size_t)(1536+tid)*8], gA + (size_t)192*HIDDEN + kc_); \
  } while(0)

#define STAGE_B(buf, kt_) do { \
    const int kc_ = (kt_)*64; \
    gload16(&sB[buf][(size_t)(tid)*8],      gB + kc_); \
    gload16(&sB[buf][(size_t)(512+tid)*8],  gB + (size_t)64*HIDDEN + kc_); \
    gload16(&sB[buf][(size_t)(1024+tid)*8], gB + (size_t)128*HIDDEN + kc_); \
  } while(0)

#define GEMM_MAIN_DB() \
  STAGE_A(0, 0); STAGE_B(0, 0); \
  for (int kt = 0; kt < 12; ++kt) { \
    const int c = kt & 1; \
    asm volatile("s_waitcnt vmcnt(0)" ::: "memory"); \
    __builtin_amdgcn_s_barrier(); \
    if (kt < 11) { STAGE_A(c^1, kt+1); STAGE_B(c^1, kt+1); } \
    const unsigned short* bA = sA[c]; \
    const unsigned short* bB = sB[c]; \
    TILE_BODY(bA, bB); \
  }

// ---------------- QKV GEMM: 768 blocks, single-buffered (2 blocks/CU) ----------------
__global__ __launch_bounds__(512, 2) void qkv_gemm(
    const unsigned short* __restrict__ A,
    const unsigned short* __restrict__ Wq,
    const unsigned short* __restrict__ Wk,
    const unsigned short* __restrict__ Wv,
    const float* __restrict__ bq,
    const float* __restrict__ bk,
    const float* __restrict__ bv,
    unsigned short* __restrict__ Qo,   // [384][512][64], pre-scaled by log2e/8
    unsigned short* __restrict__ Ko,   // [384][512][64]
    unsigned short* __restrict__ VTo)  // [384][64][512]
{
  __shared__ unsigned short sA1[16384];   // 32KB
  __shared__ unsigned short sB1[12288];   // 24KB -> 56KB total, 2 blocks/CU

  const int flat = blockIdx.x;
  const int swzb = (flat & 7) * 96 + (flat >> 3);
  const int mi_ = swzb / 12;
  const int rem = swzb % 12;
  const int mode = rem >> 2;
  const int n0 = (rem & 3) * 192;
  const int m0 = mi_ * 256;
  const unsigned short* W = (mode==0) ? Wq : ((mode==1) ? Wk : Wv);
  const float* bias = (mode==0) ? bq : ((mode==1) ? bk : bv);

  const int tid = threadIdx.x;
  const int lane = tid & 63;
  const int wid = tid >> 6;
  const int wm = wid >> 1, wn = wid & 1;    // 4m x 2n waves, wave tile 64x96
  const int g = lane >> 4, l16 = lane & 15;

  const int rS = tid >> 3;
  const int gc = (tid & 7) ^ (rS & 7);
  const unsigned short* gA = &A[(size_t)(m0 + rS)*HIDDEN + gc*8];
  const unsigned short* gB = &W[(size_t)(n0 + rS)*HIDDEN + gc*8];

  int aoff[4], boff[6];
  #pragma unroll
  for (int i = 0; i < 4; i++){
    int rm = wm*64 + i*16 + l16;
    aoff[i] = rm*64 + ((g ^ (rm&7)) * 8);
  }
  #pragma unroll
  for (int i = 0; i < 6; i++){
    int rn = wn*96 + i*16 + l16;
    boff[i] = rn*64 + ((g ^ (rn&7)) * 8);
  }

  f32x4 acc[4][6];
  #pragma unroll
  for (int i = 0; i < 4; i++)
    #pragma unroll
    for (int j = 0; j < 6; j++) acc[i][j] = (f32x4){0.f,0.f,0.f,0.f};

  GEMM_MAIN_SB();

  float bvv[6];
  #pragma unroll
  for (int ni = 0; ni < 6; ni++) bvv[ni] = bias[n0 + wn*96 + ni*16 + l16];
  #pragma unroll
  for (int mi2 = 0; mi2 < 4; mi2++) {
    int mbase = m0 + wm*64 + mi2*16 + g*4;
    int b = mbase >> 9, s = mbase & 511;
    #pragma unroll
    for (int ni = 0; ni < 6; ni++) {
      int ncol = n0 + wn*96 + ni*16 + l16;
      int h = ncol >> 6, d = ncol & 63;
      if (mode == 2) {
        us4 v;
        #pragma unroll
        for (int r = 0; r < 4; r++) v[r] = f2bf(acc[mi2][ni][r] + bvv[ni]);
        *(us4*)&VTo[(((size_t)(b*NHEAD)+h)*HDIM + d)*SEQ + s] = v;
      } else {
        #pragma unroll
        for (int r = 0; r < 4; r++) {
          float val = acc[mi2][ni][r] + bvv[ni];
          // Q pre-scaled into log2-domain: 1/8 * log2(e)
          if (mode == 0) Qo[(((size_t)(b*NHEAD)+h)*SEQ + s + r)*HDIM + d] = f2bf(val * 0.1803368801f);
          else           Ko[(((size_t)(b*NHEAD)+h)*SEQ + s + r)*HDIM + d] = f2bf(val);
        }
      }
    }
  }
}

// ---------------- output projection GEMM: 256 blocks = 1 exact round (dbuf) ----------------
__global__ __launch_bounds__(512, 2) void proj_gemm(
    const unsigned short* __restrict__ A,   // ctx bf16 [16384][768]
    const unsigned short* __restrict__ W,   // Wo bf16 [768][768]
    const float* __restrict__ bias,
    unsigned short* __restrict__ Out)       // bf16 [16384][768]
{
  __shared__ unsigned short sA[2][16384];
  __shared__ unsigned short sB[2][12288];

  const int flat = blockIdx.x;              // 256 = 8 x 32
  const int swzb = (flat & 7) * 32 + (flat >> 3);
  const int m0 = (swzb >> 2) * 256;
  const int n0 = (swzb & 3) * 192;

  const int tid = threadIdx.x;
  const int lane = tid & 63;
  const int wid = tid >> 6;
  const int wm = wid >> 1, wn = wid & 1;
  const int g = lane >> 4, l16 = lane & 15;

  const int rS = tid >> 3;
  const int gc = (tid & 7) ^ (rS & 7);
  const unsigned short* gA = &A[(size_t)(m0 + rS)*HIDDEN + gc*8];
  const unsigned short* gB = &W[(size_t)(n0 + rS)*HIDDEN + gc*8];

  int aoff[4], boff[6];
  #pragma unroll
  for (int i = 0; i < 4; i++){
    int rm = wm*64 + i*16 + l16;
    aoff[i] = rm*64 + ((g ^ (rm&7)) * 8);
  }
  #pragma unroll
  for (int i = 0; i < 6; i++){
    int rn = wn*96 + i*16 + l16;
    boff[i] = rn*64 + ((g ^ (rn&7)) * 8);
  }

  f32x4 acc[4][6];
  #pragma unroll
  for (int i = 0; i < 4; i++)
    #pragma unroll
    for (int j = 0; j < 6; j++) acc[i][j] = (f32x4){0.f,0.f,0.f,0.f};

  GEMM_MAIN_DB();

  float bvv[6];
  #pragma unroll
  for (int ni = 0; ni < 6; ni++) bvv[ni] = bias[n0 + wn*96 + ni*16 + l16];
  #pragma unroll
  for (int mi2 = 0; mi2 < 4; mi2++) {
    int mbase = m0 + wm*64 + mi2*16 + g*4;
    #pragma unroll
    for (int ni = 0; ni < 6; ni++) {
      int ncol = n0 + wn*96 + ni*16 + l16;
      #pragma unroll
      for (int r = 0; r < 4; r++)
        Out[(size_t)(mbase + r)*HIDDEN + ncol] = f2bf(acc[mi2][ni][r] + bvv[ni]);
    }
  }
}

// ---- flash attention: 8 waves / 256 q-rows, ring-2 KV, fixed-base softmax ----
__global__ __launch_bounds__(512) void attn_kernel(
    const unsigned short* __restrict__ Q,    // [384][512][64], pre-scaled by log2e/8
    const unsigned short* __restrict__ K,    // [384][512][64]
    const unsigned short* __restrict__ VT,   // [384][64][512]
    const float* __restrict__ mask,          // [32][512]
    unsigned short* __restrict__ ctx)        // [16384][768] bf16
{
  __shared__ unsigned short sK[2][4096];     // 64 rows x 64 shorts per tile
  __shared__ unsigned short sV[2][4096];
  __shared__ unsigned short P_lds[8*16*68];  // per-wave 16 rows (one q16 at a time)
  __shared__ float sMask[512];

  const int flat = blockIdx.x;               // 768 = 8 x 96
  const int swzb = (flat & 7) * 96 + (flat >> 3);
  const int qt = swzb & 1;
  const int bh = swzb >> 1;
  const int b = bh / NHEAD, h = bh % NHEAD;
  const int tid = threadIdx.x;
  const int lane = tid & 63;
  const int wid = tid >> 6;
  const int g = lane >> 4, l16 = lane & 15;
  const int qbase = qt*256 + wid*32;

  // staging: wave<4 stages K rows (wid&3)*16+(lane>>3); wave>=4 same rows of VT.
  const int srow = ((wid & 3) << 4) + (lane >> 3);     // 0..63
  const int schunk = (lane & 7) ^ (srow & 7);
  const size_t khb = (size_t)bh * SEQ;
  const unsigned short* gKs  = &K[(khb + srow)*HDIM + schunk*8];
  const unsigned short* gKs2 = gKs + (size_t)8*HDIM;
  const unsigned short* gVs  = &VT[((size_t)bh*HDIM + srow)*SEQ + schunk*8];
  const unsigned short* gVs2 = gVs + (size_t)8*SEQ;

  // mask in log2 domain (512 threads cover 512 entries)
  sMask[tid] = mask[b*SEQ + tid] * LOG2E;

  short8 aQ0[2], aQ1[2];
  #pragma unroll
  for (int q16 = 0; q16 < 2; q16++){
    const unsigned short* qp = &Q[(khb + qbase + q16*16 + l16)*HDIM];
    aQ0[q16] = *(const short8*)&qp[g*8];
    aQ1[q16] = *(const short8*)&qp[32 + g*8];
  }

  int off[4];
  {
    const int sw = (g ^ (l16 & 7)) * 8;
    #pragma unroll
    for (int i = 0; i < 4; i++) off[i] = (i*16 + l16)*64 + sw;
  }

  float l_r[2][4];
  f32x4 o_acc[2][4];
  #pragma unroll
  for (int q16 = 0; q16 < 2; q16++){
    #pragma unroll
    for (int r = 0; r < 4; r++) l_r[q16][r] = 0.f;
    #pragma unroll
    for (int dt = 0; dt < 4; dt++) o_acc[q16][dt] = (f32x4){0.f,0.f,0.f,0.f};
  }

#define KSTAGE(buf_, t_) do { \
    if (wid < 4) { \
      gload16(&sK[buf_][(size_t)((wid & 3) << 10)],       gKs  + (size_t)(t_)*64*HDIM); \
      gload16(&sK[buf_][(size_t)((wid & 3) << 10) + 512], gKs2 + (size_t)(t_)*64*HDIM); \
    } else { \
      gload16(&sV[buf_][(size_t)((wid & 3) << 10)],       gVs  + (t_)*64); \
      gload16(&sV[buf_][(size_t)((wid & 3) << 10) + 512], gVs2 + (t_)*64); \
    } \
  } while(0)

  KSTAGE(0, 0);
  // drain this wave's sMask ds_write before first barrier (vmcnt stays counted)
  asm volatile("s_waitcnt lgkmcnt(0)" ::: "memory");

  int cb = 0;
  for (int kt = 0; kt < 8; ++kt) {
    asm volatile("s_waitcnt vmcnt(0)" ::: "memory");
    __builtin_amdgcn_s_barrier();
    __builtin_amdgcn_sched_barrier(0);
    if (kt < 7) KSTAGE(cb ^ 1, kt + 1);
    const unsigned short* bK = sK[cb];
    const unsigned short* bV = sV[cb];
    const int kv0 = kt * 64;

    // QK^T (scores already in log2 domain via Q pre-scale)
    f32x4 sacc[2][4];
    #pragma unroll
    for (int ct = 0; ct < 4; ++ct) {
      short8 k0 = *(const short8*)&bK[off[ct]];
      short8 k1 = *(const short8*)&bK[off[ct] ^ 32];
      f32x4 s0 = (f32x4){0.f,0.f,0.f,0.f}, s1 = (f32x4){0.f,0.f,0.f,0.f};
      __builtin_amdgcn_s_setprio(1);
      s0 = __builtin_amdgcn_mfma_f32_16x16x32_bf16(aQ0[0], k0, s0, 0, 0, 0);
      s0 = __builtin_amdgcn_mfma_f32_16x16x32_bf16(aQ1[0], k1, s0, 0, 0, 0);
      s1 = __builtin_amdgcn_mfma_f32_16x16x32_bf16(aQ0[1], k0, s1, 0, 0, 0);
      s1 = __builtin_amdgcn_mfma_f32_16x16x32_bf16(aQ1[1], k1, s1, 0, 0, 0);
      __builtin_amdgcn_s_setprio(0);
      float mv = sMask[kv0 + ct*16 + l16];
      sacc[0][ct] = s0 + mv;
      sacc[1][ct] = s1 + mv;
    }

    // fixed-base softmax: P = 2^s; sequential q16 through the per-wave P buffer
    #pragma unroll
    for (int q16 = 0; q16 < 2; q16++){
      #pragma unroll
      for (int ct = 0; ct < 4; ct++){
        #pragma unroll
        for (int r = 0; r < 4; r++){
          float p = fexp2(sacc[q16][ct][r]);
          l_r[q16][r] += p;
          P_lds[(wid*16 + g*4 + r)*68 + ct*16 + l16] =
              (unsigned short)(__builtin_bit_cast(unsigned, p) >> 16);
        }
      }
      asm volatile("s_waitcnt lgkmcnt(0)" ::: "memory");
      __builtin_amdgcn_sched_barrier(0);
      short8 pa0 = *(const short8*)&P_lds[(wid*16 + l16)*68 + g*8];
      short8 pa1 = *(const short8*)&P_lds[(wid*16 + l16)*68 + 32 + g*8];
      __builtin_amdgcn_s_setprio(1);
      #pragma unroll
      for (int dt = 0; dt < 4; dt++){
        short8 v0 = *(const short8*)&bV[off[dt]];
        short8 v1 = *(const short8*)&bV[off[dt] ^ 32];
        o_acc[q16][dt] = __builtin_amdgcn_mfma_f32_16x16x32_bf16(pa0, v0, o_acc[q16][dt], 0, 0, 0);
        o_acc[q16][dt] = __builtin_amdgcn_mfma_f32_16x16x32_bf16(pa1, v1, o_acc[q16][dt], 0, 0, 0);
      }
      __builtin_amdgcn_s_setprio(0);
    }
    cb ^= 1;
  }

  // finalize: row-sum of l across the 16 lanes sharing g, then O/l
  #pragma unroll
  for (int q16 = 0; q16 < 2; q16++){
    #pragma unroll
    for (int o = 1; o <= 8; o <<= 1){
      #pragma unroll
      for (int r = 0; r < 4; r++) l_r[q16][r] += __shfl_xor(l_r[q16][r], o);
    }
    float inv[4];
    #pragma unroll
    for (int r = 0; r < 4; r++) inv[r] = 1.f / l_r[q16][r];
    #pragma unroll
    for (int dt = 0; dt < 4; dt++){
      #pragma unroll
      for (int r = 0; r < 4; r++){
        int s = qbase + q16*16 + g*4 + r;
        ctx[((size_t)(b*SEQ + s))*HIDDEN + h*HDIM + dt*16 + l16] = f2bf(o_acc[q16][dt][r] * inv[r]);
      }
    }
  }
#undef KSTAGE
}

// ---------------- residual + LayerNorm (x and attn_out both bf16) ----------------
__global__ __launch_bounds__(256) void resid_ln(
    const unsigned short* __restrict__ xb, const unsigned short* __restrict__ ao,
    const float* __restrict__ lnw, const float* __restrict__ lnb,
    float* __restrict__ out)
{
  const int row = blockIdx.x*4 + (threadIdx.x >> 6);
  const int lane = threadIdx.x & 63;
  const ushort4* xr = (const ushort4*)&xb[(size_t)row*HIDDEN];
  const ushort4* ar = (const ushort4*)&ao[(size_t)row*HIDDEN];
  float4 y[3];
  float s1 = 0.f, s2 = 0.f;
  #pragma unroll
  for (int j = 0; j < 3; j++){
    ushort4 xv = xr[lane + j*64];
    ushort4 av = ar[lane + j*64];
    float4 v;
    v.x = bf2f(xv.x) + bf2f(av.x); v.y = bf2f(xv.y) + bf2f(av.y);
    v.z = bf2f(xv.z) + bf2f(av.z); v.w = bf2f(xv.w) + bf2f(av.w);
    y[j] = v;
    s1 += v.x + v.y + v.z + v.w;
    s2 += v.x*v.x + v.y*v.y + v.z*v.z + v.w*v.w;
  }
  #pragma unroll
  for (int o = 1; o <= 32; o <<= 1){
    s1 += __shfl_xor(s1, o);
    s2 += __shfl_xor(s2, o);
  }
  float mean = s1 * (1.f/768.f);
  float var = s2 * (1.f/768.f) - mean*mean;
  float rstd = rsqrtf(var + 1e-12f);
  float4* orow = (float4*)&out[(size_t)row*HIDDEN];
  #pragma unroll
  for (int j = 0; j < 3; j++){
    float4 gm = ((const float4*)lnw)[lane + j*64];
    float4 bt = ((const float4*)lnb)[lane + j*64];
    float4 o;
    o.x = (y[j].x - mean)*rstd*gm.x + bt.x;
    o.y = (y[j].y - mean)*rstd*gm.y + bt.y;
    o.z = (y[j].z - mean)*rstd*gm.z + bt.z;
    o.w = (y[j].w - mean)*rstd*gm.w + bt.w;
    orow[lane + j*64] = o;
  }
}

extern "C" void kernel_launch(void* const* d_in, const int* in_sizes, int n_in,
                              void* d_out, int out_size, void* d_ws, size_t ws_size,
                              hipStream_t stream) {
  (void)in_sizes; (void)n_in; (void)out_size; (void)ws_size;
  const float* x    = (const float*)d_in[0];
  const float* mask = (const float*)d_in[1];
  const float* Wq   = (const float*)d_in[2];
  const float* bq   = (const float*)d_in[3];
  const float* Wk   = (const float*)d_in[4];
  const float* bk   = (const float*)d_in[5];
  const float* Wv   = (const float*)d_in[6];
  const float* bv   = (const float*)d_in[7];
  const float* Wo   = (const float*)d_in[8];
  const float* bo   = (const float*)d_in[9];
  const float* lnw  = (const float*)d_in[10];
  const float* lnb  = (const float*)d_in[11];
  float* out = (float*)d_out;

  char* w = (char*)d_ws;
  size_t off = 0;
  auto alloc = [&](size_t bytes) -> char* {
    char* p = w + off; off += (bytes + 255) & ~(size_t)255; return p;
  };
  unsigned short* xb  = (unsigned short*)alloc((size_t)MTOT*HIDDEN*2);
  unsigned short* wqb = (unsigned short*)alloc((size_t)HIDDEN*HIDDEN*2);
  unsigned short* wkb = (unsigned short*)alloc((size_t)HIDDEN*HIDDEN*2);
  unsigned short* wvb = (unsigned short*)alloc((size_t)HIDDEN*HIDDEN*2);
  unsigned short* wob = (unsigned short*)alloc((size_t)HIDDEN*HIDDEN*2);
  unsigned short* qb  = (unsigned short*)alloc((size_t)MTOT*HDIM*NHEAD*2);
  unsigned short* kb  = (unsigned short*)alloc((size_t)MTOT*HDIM*NHEAD*2);
  unsigned short* vtb = (unsigned short*)alloc((size_t)MTOT*HDIM*NHEAD*2);
  unsigned short* ctxb= (unsigned short*)alloc((size_t)MTOT*HIDDEN*2);
  unsigned short* attn_out = qb;   // bf16 attn_out reuses dead q region (25MB)

  cvt_all<<<dim3((XF4 + 4*WF4 + 255)/256), 256, 0, stream>>>(
      x, Wq, Wk, Wv, Wo, xb, wqb, wkb, wvb, wob);

  qkv_gemm<<<dim3(768), 512, 0, stream>>>(xb, wqb, wkb, wvb, bq, bk, bv, qb, kb, vtb);

  attn_kernel<<<dim3(768), 512, 0, stream>>>(qb, kb, vtb, mask, ctxb);

  proj_gemm<<<dim3(256), 512, 0, stream>>>(ctxb, wob, bo, attn_out);

  resid_ln<<<dim3(MTOT/4), 256, 0, stream>>>(xb, attn_out, lnw, lnb, out);
}

// Round 21
// 177.002 us; speedup vs baseline: 1.0217x; 1.0217x over previous
//
#include <hip/hip_runtime.h>

#define HIDDEN 768
#define NHEAD 12
#define HDIM 64
#define SEQ 512
#define BATCH 32
#define MTOT (BATCH*SEQ)   // 16384

typedef __attribute__((ext_vector_type(8))) short short8;
typedef __attribute__((ext_vector_type(4))) float f32x4;
typedef __attribute__((ext_vector_type(4))) unsigned short us4;

#define LOG2E 1.44269504088896340736f

__device__ __forceinline__ unsigned short f2bf(float f){
  unsigned u = __builtin_bit_cast(unsigned, f);
  u += 0x7fff + ((u >> 16) & 1);   // RNE
  return (unsigned short)(u >> 16);
}

__device__ __forceinline__ float bf2f(unsigned short s){
  unsigned u = ((unsigned)s) << 16;
  return __builtin_bit_cast(float, u);
}

// bare v_exp_f32 (2^x); s_nop covers the TRANS->consumer wait-state hazard
__device__ __forceinline__ float fexp2(float x){
  float r;
  asm("v_exp_f32 %0, %1\n\ts_nop 0" : "=v"(r) : "v"(x));
  return r;
}

__device__ __forceinline__ void gload16(unsigned short* lds, const unsigned short* g){
  __builtin_amdgcn_global_load_lds(
      (const __attribute__((address_space(1))) void*)g,
      (__attribute__((address_space(3))) void*)lds, 16, 0, 0);
}

// ---------------- fp32 -> bf16 conversion: x + 4 weights in ONE launch ----------------
#define XF4   (MTOT*HIDDEN/4)
#define WF4   (HIDDEN*HIDDEN/4)
__global__ __launch_bounds__(256) void cvt_all(
    const float* __restrict__ x,
    const float* __restrict__ w0, const float* __restrict__ w1,
    const float* __restrict__ w2, const float* __restrict__ w3,
    unsigned short* __restrict__ xo,
    unsigned short* __restrict__ o0, unsigned short* __restrict__ o1,
    unsigned short* __restrict__ o2, unsigned short* __restrict__ o3){
  int idx = blockIdx.x * blockDim.x + threadIdx.x;
  const float* in;
  unsigned short* out;
  int off;
  if (idx < XF4) { in = x; out = xo; off = idx; }
  else {
    int widx = idx - XF4;
    int which = widx / WF4;
    off = widx - which * WF4;
    in  = (which==0)?w0:((which==1)?w1:((which==2)?w2:w3));
    out = (which==0)?o0:((which==1)?o1:((which==2)?o2:o3));
  }
  float4 v = ((const float4*)in)[off];
  ushort4 o;
  o.x = f2bf(v.x); o.y = f2bf(v.y); o.z = f2bf(v.z); o.w = f2bf(v.w);
  ((ushort4*)out)[off] = o;
}

// ====== 256x192 GEMM, BK=64, 4m x 2n wave grid, counted-lgkm sub-phases (best) ======
#define STAGE_A(buf, kt_) do { \
    const int kc_ = (kt_)*64; \
    gload16(&sA[buf][(size_t)(tid)*8],      gA + kc_); \
    gload16(&sA[buf][(size_t)(512+tid)*8],  gA + (size_t)64*HIDDEN + kc_); \
    gload16(&sA[buf][(size_t)(1024+tid)*8], gA + (size_t)128*HIDDEN + kc_); \
    gload16(&sA[buf][(size_t)(1536+tid)*8], gA + (size_t)192*HIDDEN + kc_); \
  } while(0)

#define STAGE_B(buf, kt_) do { \
    const int kc_ = (kt_)*64; \
    gload16(&sB[buf][(size_t)(tid)*8],      gB + kc_); \
    gload16(&sB[buf][(size_t)(512+tid)*8],  gB + (size_t)64*HIDDEN + kc_); \
    gload16(&sB[buf][(size_t)(1024+tid)*8], gB + (size_t)128*HIDDEN + kc_); \
  } while(0)

#define GEMM_MAIN() \
  STAGE_A(0, 0); STAGE_B(0, 0); \
  for (int kt = 0; kt < 12; ++kt) { \
    const int c = kt & 1; \
    asm volatile("s_waitcnt vmcnt(0)" ::: "memory"); \
    __builtin_amdgcn_s_barrier(); \
    if (kt < 11) { STAGE_A(c^1, kt+1); STAGE_B(c^1, kt+1); } \
    const unsigned short* bA = sA[c]; \
    const unsigned short* bB = sB[c]; \
    short8 af0[4], bf0[6], af1[4], bf1[6]; \
    _Pragma("unroll") \
    for (int i = 0; i < 4; i++) af0[i] = *(const short8*)&bA[aoff[i]]; \
    _Pragma("unroll") \
    for (int i = 0; i < 6; i++) bf0[i] = *(const short8*)&bB[boff[i]]; \
    __builtin_amdgcn_sched_barrier(0); \
    _Pragma("unroll") \
    for (int i = 0; i < 4; i++) af1[i] = *(const short8*)&bA[aoff[i] ^ 32]; \
    _Pragma("unroll") \
    for (int i = 0; i < 6; i++) bf1[i] = *(const short8*)&bB[boff[i] ^ 32]; \
    asm volatile("s_waitcnt lgkmcnt(10)" ::: "memory"); \
    __builtin_amdgcn_sched_barrier(0); \
    __builtin_amdgcn_s_setprio(1); \
    _Pragma("unroll") \
    for (int mi2 = 0; mi2 < 4; mi2++) \
      _Pragma("unroll") \
      for (int ni = 0; ni < 6; ni++) \
        acc[mi2][ni] = __builtin_amdgcn_mfma_f32_16x16x32_bf16(af0[mi2], bf0[ni], acc[mi2][ni], 0, 0, 0); \
    __builtin_amdgcn_s_setprio(0); \
    asm volatile("s_waitcnt lgkmcnt(0)" ::: "memory"); \
    __builtin_amdgcn_sched_barrier(0); \
    __builtin_amdgcn_s_setprio(1); \
    _Pragma("unroll") \
    for (int mi2 = 0; mi2 < 4; mi2++) \
      _Pragma("unroll") \
      for (int ni = 0; ni < 6; ni++) \
        acc[mi2][ni] = __builtin_amdgcn_mfma_f32_16x16x32_bf16(af1[mi2], bf1[ni], acc[mi2][ni], 0, 0, 0); \
    __builtin_amdgcn_s_setprio(0); \
  }

// ---------------- QKV GEMM: 768 blocks = 3 exact rounds of 256 ----------------
__global__ __launch_bounds__(512, 2) void qkv_gemm(
    const unsigned short* __restrict__ A,
    const unsigned short* __restrict__ Wq,
    const unsigned short* __restrict__ Wk,
    const unsigned short* __restrict__ Wv,
    const float* __restrict__ bq,
    const float* __restrict__ bk,
    const float* __restrict__ bv,
    unsigned short* __restrict__ Qo,   // [384][512][64], pre-scaled by log2e/8
    unsigned short* __restrict__ Ko,   // [384][512][64]
    unsigned short* __restrict__ VTo)  // [384][64][512]
{
  __shared__ unsigned short sA[2][16384];   // 2 x 32KB
  __shared__ unsigned short sB[2][12288];   // 2 x 24KB

  const int flat = blockIdx.x;
  const int swzb = (flat & 7) * 96 + (flat >> 3);
  const int mi_ = swzb / 12;
  const int rem = swzb % 12;
  const int mode = rem >> 2;
  const int n0 = (rem & 3) * 192;
  const int m0 = mi_ * 256;
  const unsigned short* W = (mode==0) ? Wq : ((mode==1) ? Wk : Wv);
  const float* bias = (mode==0) ? bq : ((mode==1) ? bk : bv);

  const int tid = threadIdx.x;
  const int lane = tid & 63;
  const int wid = tid >> 6;
  const int wm = wid >> 1, wn = wid & 1;    // 4m x 2n waves, wave tile 64x96
  const int g = lane >> 4, l16 = lane & 15;

  const int rS = tid >> 3;
  const int gc = (tid & 7) ^ (rS & 7);
  const unsigned short* gA = &A[(size_t)(m0 + rS)*HIDDEN + gc*8];
  const unsigned short* gB = &W[(size_t)(n0 + rS)*HIDDEN + gc*8];

  int aoff[4], boff[6];
  #pragma unroll
  for (int i = 0; i < 4; i++){
    int rm = wm*64 + i*16 + l16;
    aoff[i] = rm*64 + ((g ^ (rm&7)) * 8);
  }
  #pragma unroll
  for (int i = 0; i < 6; i++){
    int rn = wn*96 + i*16 + l16;
    boff[i] = rn*64 + ((g ^ (rn&7)) * 8);
  }

  f32x4 acc[4][6];
  #pragma unroll
  for (int i = 0; i < 4; i++)
    #pragma unroll
    for (int j = 0; j < 6; j++) acc[i][j] = (f32x4){0.f,0.f,0.f,0.f};

  GEMM_MAIN();

  float bvv[6];
  #pragma unroll
  for (int ni = 0; ni < 6; ni++) bvv[ni] = bias[n0 + wn*96 + ni*16 + l16];
  #pragma unroll
  for (int mi2 = 0; mi2 < 4; mi2++) {
    int mbase = m0 + wm*64 + mi2*16 + g*4;
    int b = mbase >> 9, s = mbase & 511;
    #pragma unroll
    for (int ni = 0; ni < 6; ni++) {
      int ncol = n0 + wn*96 + ni*16 + l16;
      int h = ncol >> 6, d = ncol & 63;
      if (mode == 2) {
        us4 v;
        #pragma unroll
        for (int r = 0; r < 4; r++) v[r] = f2bf(acc[mi2][ni][r] + bvv[ni]);
        *(us4*)&VTo[(((size_t)(b*NHEAD)+h)*HDIM + d)*SEQ + s] = v;
      } else {
        #pragma unroll
        for (int r = 0; r < 4; r++) {
          float val = acc[mi2][ni][r] + bvv[ni];
          // Q pre-scaled into log2-domain: 1/8 * log2(e)
          if (mode == 0) Qo[(((size_t)(b*NHEAD)+h)*SEQ + s + r)*HDIM + d] = f2bf(val * 0.1803368801f);
          else           Ko[(((size_t)(b*NHEAD)+h)*SEQ + s + r)*HDIM + d] = f2bf(val);
        }
      }
    }
  }
}

// ---------------- output projection GEMM: 256 blocks = 1 exact round ----------------
__global__ __launch_bounds__(512, 2) void proj_gemm(
    const unsigned short* __restrict__ A,   // ctx bf16 [16384][768]
    const unsigned short* __restrict__ W,   // Wo bf16 [768][768]
    const float* __restrict__ bias,
    unsigned short* __restrict__ Out)       // bf16 [16384][768]
{
  __shared__ unsigned short sA[2][16384];
  __shared__ unsigned short sB[2][12288];

  const int flat = blockIdx.x;              // 256 = 8 x 32
  const int swzb = (flat & 7) * 32 + (flat >> 3);
  const int m0 = (swzb >> 2) * 256;
  const int n0 = (swzb & 3) * 192;

  const int tid = threadIdx.x;
  const int lane = tid & 63;
  const int wid = tid >> 6;
  const int wm = wid >> 1, wn = wid & 1;
  const int g = lane >> 4, l16 = lane & 15;

  const int rS = tid >> 3;
  const int gc = (tid & 7) ^ (rS & 7);
  const unsigned short* gA = &A[(size_t)(m0 + rS)*HIDDEN + gc*8];
  const unsigned short* gB = &W[(size_t)(n0 + rS)*HIDDEN + gc*8];

  int aoff[4], boff[6];
  #pragma unroll
  for (int i = 0; i < 4; i++){
    int rm = wm*64 + i*16 + l16;
    aoff[i] = rm*64 + ((g ^ (rm&7)) * 8);
  }
  #pragma unroll
  for (int i = 0; i < 6; i++){
    int rn = wn*96 + i*16 + l16;
    boff[i] = rn*64 + ((g ^ (rn&7)) * 8);
  }

  f32x4 acc[4][6];
  #pragma unroll
  for (int i = 0; i < 4; i++)
    #pragma unroll
    for (int j = 0; j < 6; j++) acc[i][j] = (f32x4){0.f,0.f,0.f,0.f};

  GEMM_MAIN();

  float bvv[6];
  #pragma unroll
  for (int ni = 0; ni < 6; ni++) bvv[ni] = bias[n0 + wn*96 + ni*16 + l16];
  #pragma unroll
  for (int mi2 = 0; mi2 < 4; mi2++) {
    int mbase = m0 + wm*64 + mi2*16 + g*4;
    #pragma unroll
    for (int ni = 0; ni < 6; ni++) {
      int ncol = n0 + wn*96 + ni*16 + l16;
      #pragma unroll
      for (int r = 0; r < 4; r++)
        Out[(size_t)(mbase + r)*HIDDEN + ncol] = f2bf(acc[mi2][ni][r] + bvv[ni]);
    }
  }
}

// ---- flash attention: 8 waves / 256 q-rows, ring-2 KV, fixed-base softmax ----
__global__ __launch_bounds__(512) void attn_kernel(
    const unsigned short* __restrict__ Q,    // [384][512][64], pre-scaled by log2e/8
    const unsigned short* __restrict__ K,    // [384][512][64]
    const unsigned short* __restrict__ VT,   // [384][64][512]
    const float* __restrict__ mask,          // [32][512]
    unsigned short* __restrict__ ctx)        // [16384][768] bf16
{
  __shared__ unsigned short sK[2][4096];     // 64 rows x 64 shorts per tile
  __shared__ unsigned short sV[2][4096];
  __shared__ unsigned short P_lds[8*16*68];  // per-wave 16 rows (one q16 at a time)
  __shared__ float sMask[512];

  const int flat = blockIdx.x;               // 768 = 8 x 96
  const int swzb = (flat & 7) * 96 + (flat >> 3);
  const int qt = swzb & 1;
  const int bh = swzb >> 1;
  const int b = bh / NHEAD, h = bh % NHEAD;
  const int tid = threadIdx.x;
  const int lane = tid & 63;
  const int wid = tid >> 6;
  const int g = lane >> 4, l16 = lane & 15;
  const int qbase = qt*256 + wid*32;

  // staging: wave<4 stages K rows (wid&3)*16+(lane>>3); wave>=4 same rows of VT.
  const int srow = ((wid & 3) << 4) + (lane >> 3);     // 0..63
  const int schunk = (lane & 7) ^ (srow & 7);
  const size_t khb = (size_t)bh * SEQ;
  const unsigned short* gKs  = &K[(khb + srow)*HDIM + schunk*8];
  const unsigned short* gKs2 = gKs + (size_t)8*HDIM;
  const unsigned short* gVs  = &VT[((size_t)bh*HDIM + srow)*SEQ + schunk*8];
  const unsigned short* gVs2 = gVs + (size_t)8*SEQ;

  // mask in log2 domain (512 threads cover 512 entries)
  sMask[tid] = mask[b*SEQ + tid] * LOG2E;

  short8 aQ0[2], aQ1[2];
  #pragma unroll
  for (int q16 = 0; q16 < 2; q16++){
    const unsigned short* qp = &Q[(khb + qbase + q16*16 + l16)*HDIM];
    aQ0[q16] = *(const short8*)&qp[g*8];
    aQ1[q16] = *(const short8*)&qp[32 + g*8];
  }

  int off[4];
  {
    const int sw = (g ^ (l16 & 7)) * 8;
    #pragma unroll
    for (int i = 0; i < 4; i++) off[i] = (i*16 + l16)*64 + sw;
  }

  float l_r[2][4];
  f32x4 o_acc[2][4];
  #pragma unroll
  for (int q16 = 0; q16 < 2; q16++){
    #pragma unroll
    for (int r = 0; r < 4; r++) l_r[q16][r] = 0.f;
    #pragma unroll
    for (int dt = 0; dt < 4; dt++) o_acc[q16][dt] = (f32x4){0.f,0.f,0.f,0.f};
  }

#define KSTAGE(buf_, t_) do { \
    if (wid < 4) { \
      gload16(&sK[buf_][(size_t)((wid & 3) << 10)],       gKs  + (size_t)(t_)*64*HDIM); \
      gload16(&sK[buf_][(size_t)((wid & 3) << 10) + 512], gKs2 + (size_t)(t_)*64*HDIM); \
    } else { \
      gload16(&sV[buf_][(size_t)((wid & 3) << 10)],       gVs  + (t_)*64); \
      gload16(&sV[buf_][(size_t)((wid & 3) << 10) + 512], gVs2 + (t_)*64); \
    } \
  } while(0)

  KSTAGE(0, 0);
  // drain this wave's sMask ds_write before first barrier (vmcnt stays counted)
  asm volatile("s_waitcnt lgkmcnt(0)" ::: "memory");

  int cb = 0;
  for (int kt = 0; kt < 8; ++kt) {
    asm volatile("s_waitcnt vmcnt(0)" ::: "memory");
    __builtin_amdgcn_s_barrier();
    __builtin_amdgcn_sched_barrier(0);
    if (kt < 7) KSTAGE(cb ^ 1, kt + 1);
    const unsigned short* bK = sK[cb];
    const unsigned short* bV = sV[cb];
    const int kv0 = kt * 64;

    // QK^T (scores already in log2 domain via Q pre-scale)
    f32x4 sacc[2][4];
    #pragma unroll
    for (int ct = 0; ct < 4; ++ct) {
      short8 k0 = *(const short8*)&bK[off[ct]];
      short8 k1 = *(const short8*)&bK[off[ct] ^ 32];
      f32x4 s0 = (f32x4){0.f,0.f,0.f,0.f}, s1 = (f32x4){0.f,0.f,0.f,0.f};
      __builtin_amdgcn_s_setprio(1);
      s0 = __builtin_amdgcn_mfma_f32_16x16x32_bf16(aQ0[0], k0, s0, 0, 0, 0);
      s0 = __builtin_amdgcn_mfma_f32_16x16x32_bf16(aQ1[0], k1, s0, 0, 0, 0);
      s1 = __builtin_amdgcn_mfma_f32_16x16x32_bf16(aQ0[1], k0, s1, 0, 0, 0);
      s1 = __builtin_amdgcn_mfma_f32_16x16x32_bf16(aQ1[1], k1, s1, 0, 0, 0);
      __builtin_amdgcn_s_setprio(0);
      float mv = sMask[kv0 + ct*16 + l16];
      sacc[0][ct] = s0 + mv;
      sacc[1][ct] = s1 + mv;
    }

    // fixed-base softmax: P = 2^s; sequential q16 through the per-wave P buffer
    #pragma unroll
    for (int q16 = 0; q16 < 2; q16++){
      #pragma unroll
      for (int ct = 0; ct < 4; ct++){
        #pragma unroll
        for (int r = 0; r < 4; r++){
          float p = fexp2(sacc[q16][ct][r]);
          l_r[q16][r] += p;
          P_lds[(wid*16 + g*4 + r)*68 + ct*16 + l16] =
              (unsigned short)(__builtin_bit_cast(unsigned, p) >> 16);
        }
      }
      asm volatile("s_waitcnt lgkmcnt(0)" ::: "memory");
      __builtin_amdgcn_sched_barrier(0);
      short8 pa0 = *(const short8*)&P_lds[(wid*16 + l16)*68 + g*8];
      short8 pa1 = *(const short8*)&P_lds[(wid*16 + l16)*68 + 32 + g*8];
      __builtin_amdgcn_s_setprio(1);
      #pragma unroll
      for (int dt = 0; dt < 4; dt++){
        short8 v0 = *(const short8*)&bV[off[dt]];
        short8 v1 = *(const short8*)&bV[off[dt] ^ 32];
        o_acc[q16][dt] = __builtin_amdgcn_mfma_f32_16x16x32_bf16(pa0, v0, o_acc[q16][dt], 0, 0, 0);
        o_acc[q16][dt] = __builtin_amdgcn_mfma_f32_16x16x32_bf16(pa1, v1, o_acc[q16][dt], 0, 0, 0);
      }
      __builtin_amdgcn_s_setprio(0);
    }
    cb ^= 1;
  }

  // finalize: row-sum of l across the 16 lanes sharing g, then O/l
  #pragma unroll
  for (int q16 = 0; q16 < 2; q16++){
    #pragma unroll
    for (int o = 1; o <= 8; o <<= 1){
      #pragma unroll
      for (int r = 0; r < 4; r++) l_r[q16][r] += __shfl_xor(l_r[q16][r], o);
    }
    float inv[4];
    #pragma unroll
    for (int r = 0; r < 4; r++) inv[r] = 1.f / l_r[q16][r];
    #pragma unroll
    for (int dt = 0; dt < 4; dt++){
      #pragma unroll
      for (int r = 0; r < 4; r++){
        int s = qbase + q16*16 + g*4 + r;
        ctx[((size_t)(b*SEQ + s))*HIDDEN + h*HDIM + dt*16 + l16] = f2bf(o_acc[q16][dt][r] * inv[r]);
      }
    }
  }
#undef KSTAGE
}

// ---------------- residual + LayerNorm (x and attn_out both bf16) ----------------
__global__ __launch_bounds__(256) void resid_ln(
    const unsigned short* __restrict__ xb, const unsigned short* __restrict__ ao,
    const float* __restrict__ lnw, const float* __restrict__ lnb,
    float* __restrict__ out)
{
  const int row = blockIdx.x*4 + (threadIdx.x >> 6);
  const int lane = threadIdx.x & 63;
  const ushort4* xr = (const ushort4*)&xb[(size_t)row*HIDDEN];
  const ushort4* ar = (const ushort4*)&ao[(size_t)row*HIDDEN];
  float4 y[3];
  float s1 = 0.f, s2 = 0.f;
  #pragma unroll
  for (int j = 0; j < 3; j++){
    ushort4 xv = xr[lane + j*64];
    ushort4 av = ar[lane + j*64];
    float4 v;
    v.x = bf2f(xv.x) + bf2f(av.x); v.y = bf2f(xv.y) + bf2f(av.y);
    v.z = bf2f(xv.z) + bf2f(av.z); v.w = bf2f(xv.w) + bf2f(av.w);
    y[j] = v;
    s1 += v.x + v.y + v.z + v.w;
    s2 += v.x*v.x + v.y*v.y + v.z*v.z + v.w*v.w;
  }
  #pragma unroll
  for (int o = 1; o <= 32; o <<= 1){
    s1 += __shfl_xor(s1, o);
    s2 += __shfl_xor(s2, o);
  }
  float mean = s1 * (1.f/768.f);
  float var = s2 * (1.f/768.f) - mean*mean;
  float rstd = rsqrtf(var + 1e-12f);
  float4* orow = (float4*)&out[(size_t)row*HIDDEN];
  #pragma unroll
  for (int j = 0; j < 3; j++){
    float4 gm = ((const float4*)lnw)[lane + j*64];
    float4 bt = ((const float4*)lnb)[lane + j*64];
    float4 o;
    o.x = (y[j].x - mean)*rstd*gm.x + bt.x;
    o.y = (y[j].y - mean)*rstd*gm.y + bt.y;
    o.z = (y[j].z - mean)*rstd*gm.z + bt.z;
    o.w = (y[j].w - mean)*rstd*gm.w + bt.w;
    orow[lane + j*64] = o;
  }
}

extern "C" void kernel_launch(void* const* d_in, const int* in_sizes, int n_in,
                              void* d_out, int out_size, void* d_ws, size_t ws_size,
                              hipStream_t stream) {
  (void)in_sizes; (void)n_in; (void)out_size; (void)ws_size;
  const float* x    = (const float*)d_in[0];
  const float* mask = (const float*)d_in[1];
  const float* Wq   = (const float*)d_in[2];
  const float* bq   = (const float*)d_in[3];
  const float* Wk   = (const float*)d_in[4];
  const float* bk   = (const float*)d_in[5];
  const float* Wv   = (const float*)d_in[6];
  const float* bv   = (const float*)d_in[7];
  const float* Wo   = (const float*)d_in[8];
  const float* bo   = (const float*)d_in[9];
  const float* lnw  = (const float*)d_in[10];
  const float* lnb  = (const float*)d_in[11];
  float* out = (float*)d_out;

  char* w = (char*)d_ws;
  size_t off = 0;
  auto alloc = [&](size_t bytes) -> char* {
    char* p = w + off; off += (bytes + 255) & ~(size_t)255; return p;
  };
  unsigned short* xb  = (unsigned short*)alloc((size_t)MTOT*HIDDEN*2);
  unsigned short* wqb = (unsigned short*)alloc((size_t)HIDDEN*HIDDEN*2);
  unsigned short* wkb = (unsigned short*)alloc((size_t)HIDDEN*HIDDEN*2);
  unsigned short* wvb = (unsigned short*)alloc((size_t)HIDDEN*HIDDEN*2);
  unsigned short* wob = (unsigned short*)alloc((size_t)HIDDEN*HIDDEN*2);
  unsigned short* qb  = (unsigned short*)alloc((size_t)MTOT*HDIM*NHEAD*2);
  unsigned short* kb  = (unsigned short*)alloc((size_t)MTOT*HDIM*NHEAD*2);
  unsigned short* vtb = (unsigned short*)alloc((size_t)MTOT*HDIM*NHEAD*2);
  unsigned short* ctxb= (unsigned short*)alloc((size_t)MTOT*HIDDEN*2);
  unsigned short* attn_out = qb;   // bf16 attn_out reuses dead q region (25MB)

  cvt_all<<<dim3((XF4 + 4*WF4 + 255)/256), 256, 0, stream>>>(
      x, Wq, Wk, Wv, Wo, xb, wqb, wkb, wvb, wob);

  qkv_gemm<<<dim3(768), 512, 0, stream>>>(xb, wqb, wkb, wvb, bq, bk, bv, qb, kb, vtb);

  attn_kernel<<<dim3(768), 512, 0, stream>>>(qb, kb, vtb, mask, ctxb);

  proj_gemm<<<dim3(256), 512, 0, stream>>>(ctxb, wob, bo, attn_out);

  resid_ln<<<dim3(MTOT/4), 256, 0, stream>>>(xb, attn_out, lnw, lnb, out);
}